// Round 2
// baseline (578.086 us; speedup 1.0000x reference)
//
#include <hip/hip_runtime.h>
#include <hip/hip_bf16.h>
#include <stdint.h>

#define D_ 2048
#define E_ 128
#define H_ 16
#define NB_ 2
#define NSEQ_ 2048
#define NTOK_ 4096
#define NCH_ 32

typedef short bf16s;
typedef __attribute__((ext_vector_type(8))) short bf16x8;
typedef __attribute__((ext_vector_type(4))) float f32x4;

__device__ __forceinline__ short f2b(float f) {
  __hip_bfloat16 h = __float2bfloat16(f);
  return *reinterpret_cast<short*>(&h);
}
__device__ __forceinline__ float b2f(short s) {
  __hip_bfloat16 h;
  *reinterpret_cast<short*>(&h) = s;
  return __bfloat162float(h);
}

__device__ __forceinline__ void gload_lds16(const void* g, void* l) {
  __builtin_amdgcn_global_load_lds(
      (__attribute__((address_space(1))) void*)(const_cast<void*>(g)),
      (__attribute__((address_space(3))) void*)(l), 16, 0, 0);
}

// ---------------- elementwise convert x -> bf16 ----------------
__global__ __launch_bounds__(256)
void cvt_bf16(const float* __restrict__ x, bf16s* __restrict__ y) {
  const size_t i = (size_t)blockIdx.x * 256 + threadIdx.x;
  const float4 a = ((const float4*)x)[i * 2];
  const float4 b = ((const float4*)x)[i * 2 + 1];
  bf16x8 o;
  o[0] = f2b(a.x); o[1] = f2b(a.y); o[2] = f2b(a.z); o[3] = f2b(a.w);
  o[4] = f2b(b.x); o[5] = f2b(b.y); o[6] = f2b(b.z); o[7] = f2b(b.w);
  *(bf16x8*)&y[i * 8] = o;
}

// ---------------- transpose weights f32[K][N] -> bf16[N][K] ----------------
__global__ __launch_bounds__(256)
void transpose_w(const float* __restrict__ Wq, const float* __restrict__ Wk,
                 const float* __restrict__ Wv, const float* __restrict__ Wo,
                 bf16s* __restrict__ WqT, bf16s* __restrict__ WkT,
                 bf16s* __restrict__ WvT, bf16s* __restrict__ WoT) {
  const float* src; bf16s* dst;
  if (blockIdx.z == 0)      { src = Wq; dst = WqT; }
  else if (blockIdx.z == 1) { src = Wk; dst = WkT; }
  else if (blockIdx.z == 2) { src = Wv; dst = WvT; }
  else                      { src = Wo; dst = WoT; }
  __shared__ float tile[64][65];
  const int n0 = blockIdx.x * 64, k0 = blockIdx.y * 64;
  const int t = threadIdx.x;
  const int tr = t >> 6, tc = t & 63;
#pragma unroll
  for (int rr = 0; rr < 16; ++rr) {
    const int row = rr * 4 + tr;
    tile[row][tc] = src[(size_t)(k0 + row) * D_ + n0 + tc];
  }
  __syncthreads();
#pragma unroll
  for (int rr = 0; rr < 16; ++rr) {
    const int row = rr * 4 + tr;
    dst[(size_t)(n0 + row) * D_ + k0 + tc] = f2b(tile[tc][row]);
  }
}

// ---------------- ld = log_sigmoid(x @ Wf), f32 ----------------
__global__ __launch_bounds__(256)
void ld_gemm(const float* __restrict__ x, const float* __restrict__ Wf,
             float* __restrict__ ldb) {
  const int t = threadIdx.x;
  const int col = t & 15;
  const int tok = blockIdx.x * 16 + (t >> 4);
  const float4* xr = (const float4*)(x + (size_t)tok * D_);
  float s = 0.f;
#pragma unroll 4
  for (int kk = 0; kk < D_ / 4; ++kk) {
    const float4 xv = xr[kk];
    const int k4 = kk * 4;
    s += xv.x * Wf[(k4 + 0) * H_ + col];
    s += xv.y * Wf[(k4 + 1) * H_ + col];
    s += xv.z * Wf[(k4 + 2) * H_ + col];
    s += xv.w * Wf[(k4 + 3) * H_ + col];
  }
  const float m = fminf(s, 0.f);
  ldb[(size_t)tok * H_ + col] = m - log1pf(__expf(-fabsf(s)));
}

// ---------------- bf16 MFMA GEMM, 128x128 tile, BK=32 (m97 structure) ------
// C[m][n] = act( sum_k A[m][k] * Bt[n][k] ), M=4096, N=K=2048
template <typename OT>
__device__ __forceinline__ void gemm_body(const bf16s* __restrict__ A,
                                          const bf16s* __restrict__ Bt,
                                          OT* __restrict__ Cm, int act) {
  __shared__ bf16s As[128 * 32];
  __shared__ bf16s Bs[128 * 32];
  const int bn = blockIdx.x, bm = blockIdx.y;
  const int t = threadIdx.x;
  const int w = t >> 6, l = t & 63;
  const int wm = w >> 1, wn = w & 1;
  const int lr = l & 15, lk = l >> 4;
  f32x4 acc[4][4] = {};

  const int L0 = w * 128 + l;
  const int row0 = L0 >> 2, kc0 = (L0 & 3) * 8;
  const int L1 = L0 + 64;
  const int row1 = L1 >> 2, kc1 = (L1 & 3) * 8;
  const size_t abase0 = (size_t)(bm * 128 + row0) * D_ + kc0;
  const size_t abase1 = (size_t)(bm * 128 + row1) * D_ + kc1;
  const size_t bbase0 = (size_t)(bn * 128 + row0) * D_ + kc0;
  const size_t bbase1 = (size_t)(bn * 128 + row1) * D_ + kc1;

  for (int k0 = 0; k0 < D_; k0 += 32) {
    __syncthreads();
    gload_lds16(&A[abase0 + k0], &As[(w * 128) * 8]);
    gload_lds16(&A[abase1 + k0], &As[(w * 128 + 64) * 8]);
    gload_lds16(&Bt[bbase0 + k0], &Bs[(w * 128) * 8]);
    gload_lds16(&Bt[bbase1 + k0], &Bs[(w * 128 + 64) * 8]);
    __syncthreads();
    bf16x8 af[4], bfr[4];
#pragma unroll
    for (int tm = 0; tm < 4; ++tm)
      af[tm] = *(const bf16x8*)&As[(wm * 64 + tm * 16 + lr) * 32 + lk * 8];
#pragma unroll
    for (int tn = 0; tn < 4; ++tn)
      bfr[tn] = *(const bf16x8*)&Bs[(wn * 64 + tn * 16 + lr) * 32 + lk * 8];
#pragma unroll
    for (int tm = 0; tm < 4; ++tm)
#pragma unroll
      for (int tn = 0; tn < 4; ++tn)
        acc[tm][tn] = __builtin_amdgcn_mfma_f32_16x16x32_bf16(
            af[tm], bfr[tn], acc[tm][tn], 0, 0, 0);
  }

#pragma unroll
  for (int tm = 0; tm < 4; ++tm) {
    const int rowb = bm * 128 + wm * 64 + tm * 16 + lk * 4;
#pragma unroll
    for (int tn = 0; tn < 4; ++tn) {
      const int col = bn * 128 + wn * 64 + tn * 16 + lr;
#pragma unroll
      for (int r = 0; r < 4; ++r) {
        float vv = acc[tm][tn][r];
        if (act) vv = vv / (1.f + __expf(-vv));  // silu
        if constexpr (sizeof(OT) == 2)
          Cm[(size_t)(rowb + r) * D_ + col] = f2b(vv);
        else
          Cm[(size_t)(rowb + r) * D_ + col] = vv;
      }
    }
  }
}

__global__ __launch_bounds__(256)
void gemm_qkv(const bf16s* __restrict__ xb, const bf16s* __restrict__ WqT,
              const bf16s* __restrict__ WkT, const bf16s* __restrict__ WvT,
              bf16s* __restrict__ qb, bf16s* __restrict__ kb,
              bf16s* __restrict__ vb) {
  const bf16s* Bt; bf16s* out; int act;
  if (blockIdx.z == 0)      { Bt = WqT; out = qb; act = 1; }
  else if (blockIdx.z == 1) { Bt = WkT; out = kb; act = 1; }
  else                      { Bt = WvT; out = vb; act = 0; }
  gemm_body<bf16s>(xb, Bt, out, act);
}

__global__ __launch_bounds__(256)
void gemm_out(const bf16s* __restrict__ A, const bf16s* __restrict__ Bt,
              float* __restrict__ out) {
  gemm_body<float>(A, Bt, out, 0);
}

// ---------------- chunked linear attention, one WG per (b,h) ----------------
// Tiles Qt/Kt/Vn are [64][128] bf16 (256B rows) with XOR chunk swizzle
// (byte ^= (row&7)<<4), staged via global_load_lds with pre-swizzled global
// source (rule #21). VtT/KdT/Pm are [*][64] (128B rows) with the same XOR.
__global__ __launch_bounds__(256)
void attn_kernel(const bf16s* __restrict__ q, const bf16s* __restrict__ k,
                 const bf16s* __restrict__ v, const float* __restrict__ ldp,
                 bf16s* __restrict__ o) {
  const int bh = blockIdx.x;
  const int b = bh >> 4, h = bh & 15;
  const int t = threadIdx.x;
  const int w = t >> 6, l = t & 63;
  const int lr = l & 15, lk = l >> 4;

  __shared__ bf16s Qt[64 * 128];
  __shared__ bf16s Kt[64 * 128];
  __shared__ bf16s Vn[64 * 128];
  __shared__ bf16s VtT[128 * 64];   // VtT[f][i] = v[i][f]
  __shared__ bf16s KdT[128 * 64];   // KdT[e][i] = k[i][e]*exp(tot-cum_i)
  __shared__ bf16s Tst[128 * 136];  // state S^T: Tst[f][e] = S[e][f], padded
  __shared__ bf16s Pm[64 * 64];     // masked decayed scores
  __shared__ float cumS[64];

  for (int i = t; i < 128 * 136; i += 256) Tst[i] = 0;

  char* cQt = (char*)Qt; char* cKt = (char*)Kt; char* cVn = (char*)Vn;
  char* cVtT = (char*)VtT; char* cKdT = (char*)KdT; char* cPm = (char*)Pm;

  for (int ch = 0; ch < NCH_; ++ch) {
    __syncthreads();  // prev-iter LDS reads + Tst writes complete
    const size_t grow0 = (size_t)b * NSEQ_ + ch * 64;
    // stage q,k,v tiles (rows w*16..w*16+16 per wave, 4 rows per inst)
#pragma unroll
    for (int j = 0; j < 4; ++j) {
      const int lrow = w * 16 + j * 4 + (l >> 4);
      const int ck = (l & 15) ^ (lrow & 7);  // pre-swizzled source chunk
      const size_t goff = (grow0 + lrow) * D_ + h * E_ + ck * 8;
      const int lbase = (w * 16 + j * 4) * 128;
      gload_lds16(&q[goff], &Qt[lbase]);
      gload_lds16(&k[goff], &Kt[lbase]);
      gload_lds16(&v[goff], &Vn[lbase]);
    }
    if (w == 0) {  // chunk cumsum of log-decay
      float val = ldp[(grow0 + l) * H_ + h];
#pragma unroll
      for (int off = 1; off < 64; off <<= 1) {
        float pv = __shfl_up(val, off);
        if (l >= off) val += pv;
      }
      cumS[l] = val;
    }
    __syncthreads();
    const float tot = cumS[63];

    // build VtT and scaled KdT (transposes)
#pragma unroll
    for (int it = 0; it < 4; ++it) {
      const int task = t + it * 256;
      const int i = task >> 4, c = task & 15;
      const int sb = i * 256 + ((c * 16) ^ ((i & 7) << 4));
      bf16x8 vv = *(const bf16x8*)(cVn + sb);
      bf16x8 kk8 = *(const bf16x8*)(cKt + sb);
      const float sE = __expf(tot - cumS[i]);
#pragma unroll
      for (int jj = 0; jj < 8; ++jj) {
        const int e = c * 8 + jj;
        const int db = e * 128 + ((i * 2) ^ ((e & 7) << 4));
        *(bf16s*)(cVtT + db) = vv[jj];
        *(bf16s*)(cKdT + db) = f2b(b2f(kk8[jj]) * sE);
      }
    }

    // MFMA #1 scores (q k^T) and #3 inter (q @ S, pre-update state)
    f32x4 accs[4] = {};
    f32x4 acco[8] = {};
#pragma unroll
    for (int kk = 0; kk < 4; ++kk) {
      const int cb = (kk * 32 + lk * 8) * 2;
      const int ar = w * 16 + lr;
      bf16x8 aq = *(const bf16x8*)(cQt + ar * 256 + (cb ^ ((ar & 7) << 4)));
#pragma unroll
      for (int tn = 0; tn < 4; ++tn) {
        const int br = tn * 16 + lr;
        bf16x8 bk = *(const bf16x8*)(cKt + br * 256 + (cb ^ ((br & 7) << 4)));
        accs[tn] = __builtin_amdgcn_mfma_f32_16x16x32_bf16(aq, bk, accs[tn], 0, 0, 0);
      }
#pragma unroll
      for (int tf = 0; tf < 8; ++tf) {
        bf16x8 bt = *(const bf16x8*)&Tst[(tf * 16 + lr) * 136 + kk * 32 + lk * 8];
        acco[tf] = __builtin_amdgcn_mfma_f32_16x16x32_bf16(aq, bt, acco[tf], 0, 0, 0);
      }
    }
    // row-scale the inter part by exp(cum_i)
#pragma unroll
    for (int r = 0; r < 4; ++r) {
      const float gI = __expf(cumS[w * 16 + lk * 4 + r]);
#pragma unroll
      for (int tf = 0; tf < 8; ++tf) acco[tf][r] *= gI;
    }
    // decay + causal mask -> Pm (bf16)
#pragma unroll
    for (int tn = 0; tn < 4; ++tn) {
      const int j = tn * 16 + lr;
      const float cj = cumS[j];
#pragma unroll
      for (int r = 0; r < 4; ++r) {
        const int i = w * 16 + lk * 4 + r;
        const float sv = (j <= i) ? accs[tn][r] * __expf(cumS[i] - cj) : 0.f;
        *(bf16s*)(cPm + i * 128 + ((j * 2) ^ ((i & 7) << 4))) = f2b(sv);
      }
    }
    __syncthreads();  // Pm ready; all Tst reads (#3) done

    // MFMA #2 intra: P @ V
#pragma unroll
    for (int kk2 = 0; kk2 < 2; ++kk2) {
      const int cb = (kk2 * 32 + lk * 8) * 2;
      const int pr = w * 16 + lr;
      bf16x8 ap = *(const bf16x8*)(cPm + pr * 128 + (cb ^ ((pr & 7) << 4)));
#pragma unroll
      for (int tf = 0; tf < 8; ++tf) {
        const int fr = tf * 16 + lr;
        bf16x8 bv = *(const bf16x8*)(cVtT + fr * 128 + (cb ^ ((fr & 7) << 4)));
        acco[tf] = __builtin_amdgcn_mfma_f32_16x16x32_bf16(ap, bv, acco[tf], 0, 0, 0);
      }
    }
    // write o tile
#pragma unroll
    for (int tf = 0; tf < 8; ++tf) {
#pragma unroll
      for (int r = 0; r < 4; ++r) {
        const int i = w * 16 + lk * 4 + r;
        o[(grow0 + i) * D_ + h * E_ + tf * 16 + lr] = f2b(acco[tf][r]);
      }
    }
    // MFMA #4 state update: Tst = exp(tot)*Tst + v^T @ kd  (wave owns 32 rows)
    const float dT = __expf(tot);
#pragma unroll
    for (int rt = 0; rt < 2; ++rt) {
      const int fb = w * 32 + rt * 16;
#pragma unroll
      for (int te = 0; te < 8; ++te) {
        f32x4 acct;
#pragma unroll
        for (int r = 0; r < 4; ++r)
          acct[r] = b2f(Tst[(fb + lk * 4 + r) * 136 + te * 16 + lr]) * dT;
#pragma unroll
        for (int kk2 = 0; kk2 < 2; ++kk2) {
          const int cb = (kk2 * 32 + lk * 8) * 2;
          const int vr = fb + lr;
          bf16x8 av = *(const bf16x8*)(cVtT + vr * 128 + (cb ^ ((vr & 7) << 4)));
          const int kr = te * 16 + lr;
          bf16x8 bk2 = *(const bf16x8*)(cKdT + kr * 128 + (cb ^ ((kr & 7) << 4)));
          acct = __builtin_amdgcn_mfma_f32_16x16x32_bf16(av, bk2, acct, 0, 0, 0);
        }
#pragma unroll
        for (int r = 0; r < 4; ++r)
          Tst[(fb + lk * 4 + r) * 136 + te * 16 + lr] = f2b(acct[r]);
      }
    }
  }
}

// ---------------- in-place RMS norm over D ----------------
__global__ __launch_bounds__(256)
void rmsnorm(bf16s* __restrict__ o, const float* __restrict__ nw) {
  const int tok = blockIdx.x;
  const int t = threadIdx.x;
  bf16s* row = o + (size_t)tok * D_;
  bf16x8 vv = *(bf16x8*)&row[t * 8];
  float f[8];
  float s = 0.f;
#pragma unroll
  for (int j = 0; j < 8; ++j) { f[j] = b2f(vv[j]); s += f[j] * f[j]; }
#pragma unroll
  for (int off2 = 32; off2 > 0; off2 >>= 1) s += __shfl_down(s, off2);
  __shared__ float wsum[4];
  if ((t & 63) == 0) wsum[t >> 6] = s;
  __syncthreads();
  const float scale =
      rsqrtf((wsum[0] + wsum[1] + wsum[2] + wsum[3]) * (1.f / D_) + 1e-6f);
  bf16x8 ov;
#pragma unroll
  for (int j = 0; j < 8; ++j) ov[j] = f2b(f[j] * scale * nw[t * 8 + j]);
  *(bf16x8*)&row[t * 8] = ov;
}

extern "C" void kernel_launch(void* const* d_in, const int* in_sizes, int n_in,
                              void* d_out, int out_size, void* d_ws,
                              size_t ws_size, hipStream_t stream) {
  (void)in_sizes; (void)n_in; (void)out_size;
  const float* x  = (const float*)d_in[0];
  const float* Wq = (const float*)d_in[1];
  const float* Wk = (const float*)d_in[2];
  const float* Wv = (const float*)d_in[3];
  const float* Wf = (const float*)d_in[4];
  const float* Wo = (const float*)d_in[5];
  const float* nw = (const float*)d_in[6];
  float* out = (float*)d_out;

  char* ws = (char*)d_ws;
  size_t off = 0;
  auto alloc = [&](size_t bytes) {
    char* p = ws + off;
    off += (bytes + 255) & ~(size_t)255;
    return p;
  };
  bf16s* xb  = (bf16s*)alloc((size_t)NTOK_ * D_ * 2);
  bf16s* WqT = (bf16s*)alloc((size_t)D_ * D_ * 2);
  bf16s* WkT = (bf16s*)alloc((size_t)D_ * D_ * 2);
  bf16s* WvT = (bf16s*)alloc((size_t)D_ * D_ * 2);
  bf16s* WoT = (bf16s*)alloc((size_t)D_ * D_ * 2);
  bf16s* qb  = (bf16s*)alloc((size_t)NTOK_ * D_ * 2);
  bf16s* kb  = (bf16s*)alloc((size_t)NTOK_ * D_ * 2);
  bf16s* vb  = (bf16s*)alloc((size_t)NTOK_ * D_ * 2);
  bf16s* ob  = (bf16s*)alloc((size_t)NTOK_ * D_ * 2);
  float* ldb = (float*)alloc((size_t)NTOK_ * H_ * 4);
  if (off > ws_size) return;  // workspace too small -> clean fail

  cvt_bf16<<<NTOK_ * D_ / 8 / 256, 256, 0, stream>>>(x, xb);
  transpose_w<<<dim3(32, 32, 4), 256, 0, stream>>>(Wq, Wk, Wv, Wo, WqT, WkT,
                                                   WvT, WoT);
  ld_gemm<<<NTOK_ / 16, 256, 0, stream>>>(x, Wf, ldb);
  gemm_qkv<<<dim3(16, 32, 3), 256, 0, stream>>>(xb, WqT, WkT, WvT, qb, kb, vb);
  attn_kernel<<<NB_ * H_, 256, 0, stream>>>(qb, kb, vb, ldb, ob);
  rmsnorm<<<NTOK_, 256, 0, stream>>>(ob, nw);
  gemm_out<<<dim3(16, 32), 256, 0, stream>>>(ob, WoT, out);
}

// Round 5
// 360.944 us; speedup vs baseline: 1.6016x; 1.6016x over previous
//
#include <hip/hip_runtime.h>
#include <hip/hip_bf16.h>
#include <stdint.h>

#define D_ 2048
#define E_ 128
#define H_ 16
#define NB_ 2
#define NSEQ_ 2048
#define NTOK_ 4096
#define NCH_ 32

typedef short bf16s;
typedef __attribute__((ext_vector_type(8))) short bf16x8;
typedef __attribute__((ext_vector_type(4))) float f32x4;

__device__ __forceinline__ short f2b(float f) {
  __hip_bfloat16 h = __float2bfloat16(f);
  return *reinterpret_cast<short*>(&h);
}
__device__ __forceinline__ float b2f(short s) {
  __hip_bfloat16 h;
  *reinterpret_cast<short*>(&h) = s;
  return __bfloat162float(h);
}

__device__ __forceinline__ void gload_lds16(const void* g, void* l) {
  __builtin_amdgcn_global_load_lds(
      (__attribute__((address_space(1))) void*)(const_cast<void*>(g)),
      (__attribute__((address_space(3))) void*)(l), 16, 0, 0);
}

// ---------------- elementwise convert x -> bf16 ----------------
__global__ __launch_bounds__(256)
void cvt_bf16(const float* __restrict__ x, bf16s* __restrict__ y) {
  const size_t i = (size_t)blockIdx.x * 256 + threadIdx.x;
  const float4 a = ((const float4*)x)[i * 2];
  const float4 b = ((const float4*)x)[i * 2 + 1];
  bf16x8 o;
  o[0] = f2b(a.x); o[1] = f2b(a.y); o[2] = f2b(a.z); o[3] = f2b(a.w);
  o[4] = f2b(b.x); o[5] = f2b(b.y); o[6] = f2b(b.z); o[7] = f2b(b.w);
  *(bf16x8*)&y[i * 8] = o;
}

// ---------------- transpose weights f32[K][N] -> bf16[N][K] ----------------
__global__ __launch_bounds__(256)
void transpose_w(const float* __restrict__ Wq, const float* __restrict__ Wk,
                 const float* __restrict__ Wv, const float* __restrict__ Wo,
                 bf16s* __restrict__ WqT, bf16s* __restrict__ WkT,
                 bf16s* __restrict__ WvT, bf16s* __restrict__ WoT) {
  const float* src; bf16s* dst;
  if (blockIdx.z == 0)      { src = Wq; dst = WqT; }
  else if (blockIdx.z == 1) { src = Wk; dst = WkT; }
  else if (blockIdx.z == 2) { src = Wv; dst = WvT; }
  else                      { src = Wo; dst = WoT; }
  __shared__ float tile[64][65];
  const int n0 = blockIdx.x * 64, k0 = blockIdx.y * 64;
  const int t = threadIdx.x;
  const int tr = t >> 6, tc = t & 63;
#pragma unroll
  for (int rr = 0; rr < 16; ++rr) {
    const int row = rr * 4 + tr;
    tile[row][tc] = src[(size_t)(k0 + row) * D_ + n0 + tc];
  }
  __syncthreads();
#pragma unroll
  for (int rr = 0; rr < 16; ++rr) {
    const int row = rr * 4 + tr;
    dst[(size_t)(n0 + row) * D_ + k0 + tc] = f2b(tile[tc][row]);
  }
}

// ---------------- ld = log_sigmoid(x @ Wf), f32 ----------------
__global__ __launch_bounds__(256)
void ld_gemm(const float* __restrict__ x, const float* __restrict__ Wf,
             float* __restrict__ ldb) {
  const int t = threadIdx.x;
  const int col = t & 15;
  const int tok = blockIdx.x * 16 + (t >> 4);
  const float4* xr = (const float4*)(x + (size_t)tok * D_);
  float s = 0.f;
#pragma unroll 4
  for (int kk = 0; kk < D_ / 4; ++kk) {
    const float4 xv = xr[kk];
    const int k4 = kk * 4;
    s += xv.x * Wf[(k4 + 0) * H_ + col];
    s += xv.y * Wf[(k4 + 1) * H_ + col];
    s += xv.z * Wf[(k4 + 2) * H_ + col];
    s += xv.w * Wf[(k4 + 3) * H_ + col];
  }
  const float m = fminf(s, 0.f);
  ldb[(size_t)tok * H_ + col] = m - log1pf(__expf(-fabsf(s)));
}

// ---------------- bf16 MFMA GEMM, 128x128 tile, BK=32 (m97 structure) ------
template <typename OT>
__device__ __forceinline__ void gemm_body(const bf16s* __restrict__ A,
                                          const bf16s* __restrict__ Bt,
                                          OT* __restrict__ Cm, int act) {
  __shared__ bf16s As[128 * 32];
  __shared__ bf16s Bs[128 * 32];
  const int bn = blockIdx.x, bm = blockIdx.y;
  const int t = threadIdx.x;
  const int w = t >> 6, l = t & 63;
  const int wm = w >> 1, wn = w & 1;
  const int lr = l & 15, lk = l >> 4;
  f32x4 acc[4][4] = {};

  const int L0 = w * 128 + l;
  const int row0 = L0 >> 2, kc0 = (L0 & 3) * 8;
  const int L1 = L0 + 64;
  const int row1 = L1 >> 2, kc1 = (L1 & 3) * 8;
  const size_t abase0 = (size_t)(bm * 128 + row0) * D_ + kc0;
  const size_t abase1 = (size_t)(bm * 128 + row1) * D_ + kc1;
  const size_t bbase0 = (size_t)(bn * 128 + row0) * D_ + kc0;
  const size_t bbase1 = (size_t)(bn * 128 + row1) * D_ + kc1;

  for (int k0 = 0; k0 < D_; k0 += 32) {
    __syncthreads();
    gload_lds16(&A[abase0 + k0], &As[(w * 128) * 8]);
    gload_lds16(&A[abase1 + k0], &As[(w * 128 + 64) * 8]);
    gload_lds16(&Bt[bbase0 + k0], &Bs[(w * 128) * 8]);
    gload_lds16(&Bt[bbase1 + k0], &Bs[(w * 128 + 64) * 8]);
    __syncthreads();
    bf16x8 af[4], bfr[4];
#pragma unroll
    for (int tm = 0; tm < 4; ++tm)
      af[tm] = *(const bf16x8*)&As[(wm * 64 + tm * 16 + lr) * 32 + lk * 8];
#pragma unroll
    for (int tn = 0; tn < 4; ++tn)
      bfr[tn] = *(const bf16x8*)&Bs[(wn * 64 + tn * 16 + lr) * 32 + lk * 8];
#pragma unroll
    for (int tm = 0; tm < 4; ++tm)
#pragma unroll
      for (int tn = 0; tn < 4; ++tn)
        acc[tm][tn] = __builtin_amdgcn_mfma_f32_16x16x32_bf16(
            af[tm], bfr[tn], acc[tm][tn], 0, 0, 0);
  }

#pragma unroll
  for (int tm = 0; tm < 4; ++tm) {
    const int rowb = bm * 128 + wm * 64 + tm * 16 + lk * 4;
#pragma unroll
    for (int tn = 0; tn < 4; ++tn) {
      const int col = bn * 128 + wn * 64 + tn * 16 + lr;
#pragma unroll
      for (int r = 0; r < 4; ++r) {
        float vv = acc[tm][tn][r];
        if (act) vv = vv / (1.f + __expf(-vv));  // silu
        if constexpr (sizeof(OT) == 2)
          Cm[(size_t)(rowb + r) * D_ + col] = f2b(vv);
        else
          Cm[(size_t)(rowb + r) * D_ + col] = vv;
      }
    }
  }
}

__global__ __launch_bounds__(256)
void gemm_qkv(const bf16s* __restrict__ xb, const bf16s* __restrict__ WqT,
              const bf16s* __restrict__ WkT, const bf16s* __restrict__ WvT,
              bf16s* __restrict__ qb, bf16s* __restrict__ kb,
              bf16s* __restrict__ vb) {
  const bf16s* Bt; bf16s* out; int act;
  if (blockIdx.z == 0)      { Bt = WqT; out = qb; act = 1; }
  else if (blockIdx.z == 1) { Bt = WkT; out = kb; act = 1; }
  else                      { Bt = WvT; out = vb; act = 0; }
  gemm_body<bf16s>(xb, Bt, out, act);
}

__global__ __launch_bounds__(256)
void gemm_out(const bf16s* __restrict__ A, const bf16s* __restrict__ Bt,
              float* __restrict__ out) {
  gemm_body<float>(A, Bt, out, 0);
}

// ============ chunked linear attention, 3-pass parallel decomposition =======
// Pass 1: per (b,h,c): M_c[f][e] = sum_i v_i[f] * k_i[e] * exp(tot-cum_i)
__global__ __launch_bounds__(256)
void chunk_state(const bf16s* __restrict__ k, const bf16s* __restrict__ v,
                 const float* __restrict__ ldp, bf16s* __restrict__ Mbuf,
                 float* __restrict__ totb) {
  const int c = blockIdx.x, bh = blockIdx.y;
  const int b = bh >> 4, h = bh & 15;
  const int t = threadIdx.x;
  const int w = t >> 6, l = t & 63;
  const int lr = l & 15, lk = l >> 4;

  __shared__ bf16s Kt[64 * 128];
  __shared__ bf16s Vn[64 * 128];
  __shared__ bf16s KdT[128 * 64];
  __shared__ bf16s VtT[128 * 64];
  __shared__ float cumS[64];
  char* cKt = (char*)Kt; char* cVn = (char*)Vn;
  char* cKdT = (char*)KdT; char* cVtT = (char*)VtT;

  const size_t grow0 = (size_t)b * NSEQ_ + c * 64;
#pragma unroll
  for (int j = 0; j < 4; ++j) {
    const int lrow = w * 16 + j * 4 + (l >> 4);
    const int ck = (l & 15) ^ (lrow & 7);
    const size_t goff = (grow0 + lrow) * D_ + h * E_ + ck * 8;
    const int lbase = (w * 16 + j * 4) * 128;
    gload_lds16(&k[goff], &Kt[lbase]);
    gload_lds16(&v[goff], &Vn[lbase]);
  }
  if (w == 0) {
    float val = ldp[(grow0 + l) * H_ + h];
#pragma unroll
    for (int off = 1; off < 64; off <<= 1) {
      float pv = __shfl_up(val, off);
      if (l >= off) val += pv;
    }
    cumS[l] = val;
  }
  __syncthreads();
  const float tot = cumS[63];
  if (t == 0) totb[bh * NCH_ + c] = tot;

  // transposes: VtT[f][i]=v_i[f], KdT[e][i]=k_i[e]*exp(tot-cum_i)
#pragma unroll
  for (int it = 0; it < 4; ++it) {
    const int task = t + it * 256;
    const int i = task >> 4, cx = task & 15;
    const int sb = i * 256 + ((cx * 16) ^ ((i & 7) << 4));
    bf16x8 vv = *(const bf16x8*)(cVn + sb);
    bf16x8 kk8 = *(const bf16x8*)(cKt + sb);
    const float sE = __expf(tot - cumS[i]);
#pragma unroll
    for (int jj = 0; jj < 8; ++jj) {
      const int e = cx * 8 + jj;
      const int db = e * 128 + ((i * 2) ^ ((e & 7) << 4));
      *(bf16s*)(cVtT + db) = vv[jj];
      *(bf16s*)(cKdT + db) = f2b(b2f(kk8[jj]) * sE);
    }
  }
  __syncthreads();

  const int wm = w >> 1, wn = w & 1;
  f32x4 acc[4][4] = {};
#pragma unroll
  for (int kk2 = 0; kk2 < 2; ++kk2) {
    const int cb = (kk2 * 32 + lk * 8) * 2;
    bf16x8 af[4], bfr[4];
#pragma unroll
    for (int tm = 0; tm < 4; ++tm) {
      const int fr = wm * 64 + tm * 16 + lr;
      af[tm] = *(const bf16x8*)(cVtT + fr * 128 + (cb ^ ((fr & 7) << 4)));
    }
#pragma unroll
    for (int tn = 0; tn < 4; ++tn) {
      const int er = wn * 64 + tn * 16 + lr;
      bfr[tn] = *(const bf16x8*)(cKdT + er * 128 + (cb ^ ((er & 7) << 4)));
    }
#pragma unroll
    for (int tm = 0; tm < 4; ++tm)
#pragma unroll
      for (int tn = 0; tn < 4; ++tn)
        acc[tm][tn] = __builtin_amdgcn_mfma_f32_16x16x32_bf16(
            af[tm], bfr[tn], acc[tm][tn], 0, 0, 0);
  }
  const size_t mb = (size_t)(bh * NCH_ + c) * 128 * 128;
#pragma unroll
  for (int tm = 0; tm < 4; ++tm) {
#pragma unroll
    for (int tn = 0; tn < 4; ++tn) {
#pragma unroll
      for (int r = 0; r < 4; ++r) {
        const int f = wm * 64 + tm * 16 + lk * 4 + r;
        const int e = wn * 64 + tn * 16 + lr;
        Mbuf[mb + f * 128 + e] = f2b(acc[tm][tn][r]);
      }
    }
  }
}

// Pass 2: prefix scan over chunks: S_{c+1} = exp(tot_c)*S_c + M_c.
// Writes S_c (state BEFORE chunk c), layout [bh][c][f][e] bf16.
__global__ __launch_bounds__(256)
void state_scan(const bf16s* __restrict__ Mbuf, const float* __restrict__ totb,
                bf16s* __restrict__ Sbuf) {
  const int sl = blockIdx.x;   // f-slice 0..7
  const int bh = blockIdx.y;   // 0..31
  const int t = threadIdx.x;
  const int fr = sl * 16 + (t >> 4);
  const int e0 = (t & 15) * 8;
  const size_t base = ((size_t)(bh * NCH_) * 128 + fr) * 128 + e0;
  const size_t cstride = 128 * 128;
  float acc[8] = {};
  bf16x8 m = *(const bf16x8*)&Mbuf[base];
  for (int c = 0; c < NCH_; ++c) {
    bf16x8 sv;
#pragma unroll
    for (int j = 0; j < 8; ++j) sv[j] = f2b(acc[j]);
    *(bf16x8*)&Sbuf[base + (size_t)c * cstride] = sv;
    bf16x8 mn = m;
    if (c + 1 < NCH_) mn = *(const bf16x8*)&Mbuf[base + (size_t)(c + 1) * cstride];
    const float dt = __expf(totb[bh * NCH_ + c]);
#pragma unroll
    for (int j = 0; j < 8; ++j) acc[j] = acc[j] * dt + b2f(m[j]);
    m = mn;
  }
}

// Pass 3: per (b,h,c): o = intra(q,k,v,decay) + exp(cum_i) * q @ S_c
__global__ __launch_bounds__(256)
void attn_out(const bf16s* __restrict__ q, const bf16s* __restrict__ k,
              const bf16s* __restrict__ v, const float* __restrict__ ldp,
              const bf16s* __restrict__ Sbuf, bf16s* __restrict__ o) {
  const int c = blockIdx.x, bh = blockIdx.y;
  const int b = bh >> 4, h = bh & 15;
  const int t = threadIdx.x;
  const int w = t >> 6, l = t & 63;
  const int lr = l & 15, lk = l >> 4;

  __shared__ bf16s Qt[64 * 128];
  __shared__ bf16s Kt[64 * 128];
  __shared__ bf16s Vn[64 * 128];
  __shared__ bf16s VtT[128 * 64];
  __shared__ bf16s St[128 * 128];  // S^T[f][e], swizzled
  __shared__ bf16s Pm[64 * 64];
  __shared__ float cumS[64];
  char* cQt = (char*)Qt; char* cKt = (char*)Kt; char* cVn = (char*)Vn;
  char* cVtT = (char*)VtT; char* cSt = (char*)St; char* cPm = (char*)Pm;

  const size_t grow0 = (size_t)b * NSEQ_ + c * 64;
  const size_t sbase = (size_t)(bh * NCH_ + c) * 128 * 128;
#pragma unroll
  for (int j = 0; j < 4; ++j) {
    const int lrow = w * 16 + j * 4 + (l >> 4);
    const int ck = (l & 15) ^ (lrow & 7);
    const size_t goff = (grow0 + lrow) * D_ + h * E_ + ck * 8;
    const int lbase = (w * 16 + j * 4) * 128;
    gload_lds16(&q[goff], &Qt[lbase]);
    gload_lds16(&k[goff], &Kt[lbase]);
    gload_lds16(&v[goff], &Vn[lbase]);
  }
#pragma unroll
  for (int j = 0; j < 8; ++j) {
    const int lrow = w * 32 + j * 4 + (l >> 4);
    const int ck = (l & 15) ^ (lrow & 7);
    gload_lds16(&Sbuf[sbase + (size_t)lrow * 128 + ck * 8],
                &St[(w * 32 + j * 4) * 128]);
  }
  if (w == 0) {
    float val = ldp[(grow0 + l) * H_ + h];
#pragma unroll
    for (int off = 1; off < 64; off <<= 1) {
      float pv = __shfl_up(val, off);
      if (l >= off) val += pv;
    }
    cumS[l] = val;
  }
  __syncthreads();

  // VtT[f][i] = v_i[f]
#pragma unroll
  for (int it = 0; it < 4; ++it) {
    const int task = t + it * 256;
    const int i = task >> 4, cx = task & 15;
    const int sb = i * 256 + ((cx * 16) ^ ((i & 7) << 4));
    bf16x8 vv = *(const bf16x8*)(cVn + sb);
#pragma unroll
    for (int jj = 0; jj < 8; ++jj) {
      const int e = cx * 8 + jj;
      const int db = e * 128 + ((i * 2) ^ ((e & 7) << 4));
      *(bf16s*)(cVtT + db) = vv[jj];
    }
  }

  f32x4 accs[4] = {};
  f32x4 acco[8] = {};
#pragma unroll
  for (int kk = 0; kk < 4; ++kk) {
    const int cb = (kk * 32 + lk * 8) * 2;
    const int ar = w * 16 + lr;
    bf16x8 aq = *(const bf16x8*)(cQt + ar * 256 + (cb ^ ((ar & 7) << 4)));
#pragma unroll
    for (int tn = 0; tn < 4; ++tn) {
      const int br = tn * 16 + lr;
      bf16x8 bk = *(const bf16x8*)(cKt + br * 256 + (cb ^ ((br & 7) << 4)));
      accs[tn] = __builtin_amdgcn_mfma_f32_16x16x32_bf16(aq, bk, accs[tn], 0, 0, 0);
    }
#pragma unroll
    for (int tf = 0; tf < 8; ++tf) {
      const int sr = tf * 16 + lr;
      bf16x8 bs = *(const bf16x8*)(cSt + sr * 256 + (cb ^ ((sr & 7) << 4)));
      acco[tf] = __builtin_amdgcn_mfma_f32_16x16x32_bf16(aq, bs, acco[tf], 0, 0, 0);
    }
  }
#pragma unroll
  for (int r = 0; r < 4; ++r) {
    const float gI = __expf(cumS[w * 16 + lk * 4 + r]);
#pragma unroll
    for (int tf = 0; tf < 8; ++tf) acco[tf][r] *= gI;
  }
#pragma unroll
  for (int tn = 0; tn < 4; ++tn) {
    const int j = tn * 16 + lr;
    const float cj = cumS[j];
#pragma unroll
    for (int r = 0; r < 4; ++r) {
      const int i = w * 16 + lk * 4 + r;
      const float sv = (j <= i) ? accs[tn][r] * __expf(cumS[i] - cj) : 0.f;
      *(bf16s*)(cPm + i * 128 + ((j * 2) ^ ((i & 7) << 4))) = f2b(sv);
    }
  }
  __syncthreads();

#pragma unroll
  for (int kk2 = 0; kk2 < 2; ++kk2) {
    const int cb = (kk2 * 32 + lk * 8) * 2;
    const int pr = w * 16 + lr;
    bf16x8 ap = *(const bf16x8*)(cPm + pr * 128 + (cb ^ ((pr & 7) << 4)));
#pragma unroll
    for (int tf = 0; tf < 8; ++tf) {
      const int fr = tf * 16 + lr;
      bf16x8 bv = *(const bf16x8*)(cVtT + fr * 128 + (cb ^ ((fr & 7) << 4)));
      acco[tf] = __builtin_amdgcn_mfma_f32_16x16x32_bf16(ap, bv, acco[tf], 0, 0, 0);
    }
  }
#pragma unroll
  for (int tf = 0; tf < 8; ++tf) {
#pragma unroll
    for (int r = 0; r < 4; ++r) {
      const int i = w * 16 + lk * 4 + r;
      o[(grow0 + i) * D_ + h * E_ + tf * 16 + lr] = f2b(acco[tf][r]);
    }
  }
}

// ---------------- in-place RMS norm over D ----------------
__global__ __launch_bounds__(256)
void rmsnorm(bf16s* __restrict__ o, const float* __restrict__ nw) {
  const int tok = blockIdx.x;
  const int t = threadIdx.x;
  bf16s* row = o + (size_t)tok * D_;
  bf16x8 vv = *(bf16x8*)&row[t * 8];
  float f[8];
  float s = 0.f;
#pragma unroll
  for (int j = 0; j < 8; ++j) { f[j] = b2f(vv[j]); s += f[j] * f[j]; }
#pragma unroll
  for (int off2 = 32; off2 > 0; off2 >>= 1) s += __shfl_down(s, off2);
  __shared__ float wsum[4];
  if ((t & 63) == 0) wsum[t >> 6] = s;
  __syncthreads();
  const float scale =
      rsqrtf((wsum[0] + wsum[1] + wsum[2] + wsum[3]) * (1.f / D_) + 1e-6f);
  bf16x8 ov;
#pragma unroll
  for (int j = 0; j < 8; ++j) ov[j] = f2b(f[j] * scale * nw[t * 8 + j]);
  *(bf16x8*)&row[t * 8] = ov;
}

extern "C" void kernel_launch(void* const* d_in, const int* in_sizes, int n_in,
                              void* d_out, int out_size, void* d_ws,
                              size_t ws_size, hipStream_t stream) {
  (void)in_sizes; (void)n_in; (void)out_size;
  const float* x  = (const float*)d_in[0];
  const float* Wq = (const float*)d_in[1];
  const float* Wk = (const float*)d_in[2];
  const float* Wv = (const float*)d_in[3];
  const float* Wf = (const float*)d_in[4];
  const float* Wo = (const float*)d_in[5];
  const float* nw = (const float*)d_in[6];
  float* out = (float*)d_out;

  char* ws = (char*)d_ws;
  const size_t MB = 1024 * 1024;
  // Region A (0..40MB): xb + WqT/WkT/WvT early; Sbuf + totb after gemm_qkv.
  bf16s* xb   = (bf16s*)(ws + 0);
  bf16s* WqT  = (bf16s*)(ws + 16 * MB);
  bf16s* WkT  = (bf16s*)(ws + 24 * MB);
  bf16s* WvT  = (bf16s*)(ws + 32 * MB);
  bf16s* Sbuf = (bf16s*)(ws + 0);        // alias: live after gemm_qkv
  float* totb = (float*)(ws + 32 * MB);  // alias: live after gemm_qkv
  bf16s* WoT  = (bf16s*)(ws + 40 * MB);
  bf16s* qb   = (bf16s*)(ws + 48 * MB);
  bf16s* kb   = (bf16s*)(ws + 64 * MB);
  bf16s* vb   = (bf16s*)(ws + 80 * MB);
  bf16s* ob   = (bf16s*)(ws + 96 * MB);
  bf16s* Mbuf = (bf16s*)(ws + 112 * MB);
  float* ldb  = (float*)(ws + 144 * MB);
  if (145 * MB > ws_size) return;  // workspace too small -> clean fail

  cvt_bf16<<<NTOK_ * D_ / 8 / 256, 256, 0, stream>>>(x, xb);
  transpose_w<<<dim3(32, 32, 4), 256, 0, stream>>>(Wq, Wk, Wv, Wo, WqT, WkT,
                                                   WvT, WoT);
  ld_gemm<<<NTOK_ / 16, 256, 0, stream>>>(x, Wf, ldb);
  gemm_qkv<<<dim3(16, 32, 3), 256, 0, stream>>>(xb, WqT, WkT, WvT, qb, kb, vb);
  chunk_state<<<dim3(NCH_, NB_ * H_), 256, 0, stream>>>(kb, vb, ldb, Mbuf, totb);
  state_scan<<<dim3(8, NB_ * H_), 256, 0, stream>>>(Mbuf, totb, Sbuf);
  attn_out<<<dim3(NCH_, NB_ * H_), 256, 0, stream>>>(qb, kb, vb, ldb, Sbuf, ob);
  rmsnorm<<<NTOK_, 256, 0, stream>>>(ob, nw);
  gemm_out<<<dim3(16, 32), 256, 0, stream>>>(ob, WoT, out);
}

// Round 6
// 341.918 us; speedup vs baseline: 1.6907x; 1.0556x over previous
//
#include <hip/hip_runtime.h>
#include <hip/hip_bf16.h>
#include <stdint.h>

#define D_ 2048
#define E_ 128
#define H_ 16
#define NB_ 2
#define NSEQ_ 2048
#define NTOK_ 4096
#define NCH_ 32

typedef short bf16s;
typedef __attribute__((ext_vector_type(8))) short bf16x8;
typedef __attribute__((ext_vector_type(4))) float f32x4;

__device__ __forceinline__ short f2b(float f) {
  __hip_bfloat16 h = __float2bfloat16(f);
  return *reinterpret_cast<short*>(&h);
}
__device__ __forceinline__ float b2f(short s) {
  __hip_bfloat16 h;
  *reinterpret_cast<short*>(&h) = s;
  return __bfloat162float(h);
}

__device__ __forceinline__ void gload_lds16(const void* g, void* l) {
  __builtin_amdgcn_global_load_lds(
      (__attribute__((address_space(1))) void*)(const_cast<void*>(g)),
      (__attribute__((address_space(3))) void*)(l), 16, 0, 0);
}

__device__ __forceinline__ void barrier_mem() {
  asm volatile("s_barrier" ::: "memory");
}
template <int N>
__device__ __forceinline__ void wait_vmcnt() {
  if constexpr (N == 0) asm volatile("s_waitcnt vmcnt(0)" ::: "memory");
  else if constexpr (N == 1) asm volatile("s_waitcnt vmcnt(1)" ::: "memory");
  else asm volatile("s_waitcnt vmcnt(2)" ::: "memory");
}

// ---------------- elementwise convert x -> bf16 ----------------
__global__ __launch_bounds__(256)
void cvt_bf16(const float* __restrict__ x, bf16s* __restrict__ y) {
  const size_t i = (size_t)blockIdx.x * 256 + threadIdx.x;
  const float4 a = ((const float4*)x)[i * 2];
  const float4 b = ((const float4*)x)[i * 2 + 1];
  bf16x8 o;
  o[0] = f2b(a.x); o[1] = f2b(a.y); o[2] = f2b(a.z); o[3] = f2b(a.w);
  o[4] = f2b(b.x); o[5] = f2b(b.y); o[6] = f2b(b.z); o[7] = f2b(b.w);
  *(bf16x8*)&y[i * 8] = o;
}

// ---------------- transpose weights f32[K][N] -> bf16[N][K] ----------------
__global__ __launch_bounds__(256)
void transpose_w(const float* __restrict__ Wq, const float* __restrict__ Wk,
                 const float* __restrict__ Wv, const float* __restrict__ Wo,
                 bf16s* __restrict__ WqT, bf16s* __restrict__ WkT,
                 bf16s* __restrict__ WvT, bf16s* __restrict__ WoT) {
  const float* src; bf16s* dst;
  if (blockIdx.z == 0)      { src = Wq; dst = WqT; }
  else if (blockIdx.z == 1) { src = Wk; dst = WkT; }
  else if (blockIdx.z == 2) { src = Wv; dst = WvT; }
  else                      { src = Wo; dst = WoT; }
  __shared__ float tile[64][65];
  const int n0 = blockIdx.x * 64, k0 = blockIdx.y * 64;
  const int t = threadIdx.x;
  const int tr = t >> 6, tc = t & 63;
#pragma unroll
  for (int rr = 0; rr < 16; ++rr) {
    const int row = rr * 4 + tr;
    tile[row][tc] = src[(size_t)(k0 + row) * D_ + n0 + tc];
  }
  __syncthreads();
#pragma unroll
  for (int rr = 0; rr < 16; ++rr) {
    const int row = rr * 4 + tr;
    dst[(size_t)(n0 + row) * D_ + k0 + tc] = f2b(tile[tc][row]);
  }
}

// ---------------- ld = log_sigmoid(x @ Wf), f32 ----------------
__global__ __launch_bounds__(256)
void ld_gemm(const float* __restrict__ x, const float* __restrict__ Wf,
             float* __restrict__ ldb) {
  const int t = threadIdx.x;
  const int col = t & 15;
  const int tok = blockIdx.x * 16 + (t >> 4);
  const float4* xr = (const float4*)(x + (size_t)tok * D_);
  float s = 0.f;
#pragma unroll 4
  for (int kk = 0; kk < D_ / 4; ++kk) {
    const float4 xv = xr[kk];
    const int k4 = kk * 4;
    s += xv.x * Wf[(k4 + 0) * H_ + col];
    s += xv.y * Wf[(k4 + 1) * H_ + col];
    s += xv.z * Wf[(k4 + 2) * H_ + col];
    s += xv.w * Wf[(k4 + 3) * H_ + col];
  }
  const float m = fminf(s, 0.f);
  ldb[(size_t)tok * H_ + col] = m - log1pf(__expf(-fabsf(s)));
}

// ======== 256-wide 8-phase bf16 MFMA GEMM (T2+T3+T4+T5), BK=64 =============
// C[m][n] = act( sum_k A[m][k] * Bt[n][k] ).  BM=256 fixed, BN=256 or 128.
// LDS tiles row-major [rows][64] with chunk-XOR swizzle cc^=(row&7), staged
// via global_load_lds from pre-swizzled global source (rule #21).
template <int BN, typename OT>
__device__ __forceinline__ void gemm8p_body(const bf16s* __restrict__ A,
                                            const bf16s* __restrict__ Bt,
                                            OT* __restrict__ C, int bm, int bn,
                                            int act) {
  constexpr int BM = 256, BK = 64;
  constexpr int KT = D_ / BK;   // 32 K-tiles
  constexpr int RA = BM / 64;   // A stage rounds per tile
  constexpr int RB = BN / 64;   // B stage rounds per tile
  constexpr int RT = RA + RB;   // total gloads/thread/tile (8 or 6)
  constexpr int NF = BN / 64;   // n-frags per wave (4 or 2)
  __shared__ bf16s As[2][BM * BK];
  __shared__ bf16s Bs[2][BN * BK];

  const int t = threadIdx.x;
  const int w = t >> 6, l = t & 63;
  const int wm = w >> 2, wn = w & 3;      // 2 x 4 wave grid
  const int lr = l & 15, lk = l >> 4;     // mfma lane coords
  const int lrow8 = l >> 3, lc = l & 7;   // staging lane coords
  const int csrc = lc ^ lrow8;            // pre-swizzled source chunk

  f32x4 acc[8][NF] = {};

  const size_t arow = (size_t)bm * BM;
  const size_t brow = (size_t)bn * BN;

  auto stage_round = [&](int r, int buf, int k0) {
    if (r < RA) {
      const int row0 = r * 64 + w * 8;
      gload_lds16(&A[(arow + row0 + lrow8) * D_ + k0 + csrc * 8],
                  &As[buf][row0 * BK]);
    } else {
      const int row0 = (r - RA) * 64 + w * 8;
      gload_lds16(&Bt[(brow + row0 + lrow8) * D_ + k0 + csrc * 8],
                  &Bs[buf][row0 * BK]);
    }
  };
  auto lda = [&](int buf, int fm, int ks) -> bf16x8 {
    const int row = wm * 128 + fm * 16 + lr;
    const int cc = (ks * 4 + lk) ^ (row & 7);
    return *(const bf16x8*)&As[buf][row * BK + cc * 8];
  };
  auto ldb_ = [&](int buf, int fn, int ks) -> bf16x8 {
    const int row = wn * (NF * 16) + fn * 16 + lr;
    const int cc = (ks * 4 + lk) ^ (row & 7);
    return *(const bf16x8*)&Bs[buf][row * BK + cc * 8];
  };

  // prologue: stage tile 0 -> buf 0
#pragma unroll
  for (int r = 0; r < RT; ++r) stage_round(r, 0, 0);

  bf16x8 bfr[NF][2];
  for (int tki = 0; tki < KT - 1; ++tki) {
    const int cur = tki & 1, nxt = cur ^ 1;
    const int k0n = (tki + 1) * BK;
#pragma unroll
    for (int qd = 0; qd < 4; ++qd) {
      const int r0 = (qd * RT) / 4, r1 = ((qd + 1) * RT) / 4;
      if (qd == 0) {
        // issue first prefetch rounds, then wait for THIS tile's loads only
#pragma unroll
        for (int r = r0; r < r1; ++r) stage_round(r, nxt, k0n);
        wait_vmcnt<RT / 4>();
        barrier_mem();
#pragma unroll
        for (int fn = 0; fn < NF; ++fn)
#pragma unroll
          for (int ks = 0; ks < 2; ++ks) bfr[fn][ks] = ldb_(cur, fn, ks);
      }
      bf16x8 af[2][2];
#pragma unroll
      for (int f2 = 0; f2 < 2; ++f2)
#pragma unroll
        for (int ks = 0; ks < 2; ++ks) af[f2][ks] = lda(cur, qd * 2 + f2, ks);
      if (qd != 0) {
#pragma unroll
        for (int r = r0; r < r1; ++r) stage_round(r, nxt, k0n);
        barrier_mem();
      }
      __builtin_amdgcn_s_setprio(1);
#pragma unroll
      for (int f2 = 0; f2 < 2; ++f2)
#pragma unroll
        for (int fn = 0; fn < NF; ++fn)
#pragma unroll
          for (int ks = 0; ks < 2; ++ks)
            acc[qd * 2 + f2][fn] = __builtin_amdgcn_mfma_f32_16x16x32_bf16(
                af[f2][ks], bfr[fn][ks], acc[qd * 2 + f2][fn], 0, 0, 0);
      __builtin_amdgcn_s_setprio(0);
      barrier_mem();
    }
  }
  // peeled last tile: full drain, no staging
  {
    const int cur = (KT - 1) & 1;
    wait_vmcnt<0>();
    barrier_mem();
#pragma unroll
    for (int fn = 0; fn < NF; ++fn)
#pragma unroll
      for (int ks = 0; ks < 2; ++ks) bfr[fn][ks] = ldb_(cur, fn, ks);
#pragma unroll
    for (int qd = 0; qd < 4; ++qd) {
      bf16x8 af[2][2];
#pragma unroll
      for (int f2 = 0; f2 < 2; ++f2)
#pragma unroll
        for (int ks = 0; ks < 2; ++ks) af[f2][ks] = lda(cur, qd * 2 + f2, ks);
#pragma unroll
      for (int f2 = 0; f2 < 2; ++f2)
#pragma unroll
        for (int fn = 0; fn < NF; ++fn)
#pragma unroll
          for (int ks = 0; ks < 2; ++ks)
            acc[qd * 2 + f2][fn] = __builtin_amdgcn_mfma_f32_16x16x32_bf16(
                af[f2][ks], bfr[fn][ks], acc[qd * 2 + f2][fn], 0, 0, 0);
    }
  }
  // epilogue
#pragma unroll
  for (int fm = 0; fm < 8; ++fm) {
    const int row = bm * BM + wm * 128 + fm * 16 + lk * 4;
#pragma unroll
    for (int fn = 0; fn < NF; ++fn) {
      const int col = bn * BN + wn * (NF * 16) + fn * 16 + lr;
#pragma unroll
      for (int r = 0; r < 4; ++r) {
        float vv = acc[fm][fn][r];
        if (act) vv = vv / (1.f + __expf(-vv));  // silu
        if constexpr (sizeof(OT) == 2)
          C[(size_t)(row + r) * D_ + col] = f2b(vv);
        else
          C[(size_t)(row + r) * D_ + col] = vv;
      }
    }
  }
}

// fused q,k,v projections: grid (24, 16) — bn 0..7 q, 8..15 k, 16..23 v
__global__ __launch_bounds__(512, 2)
void gemm_qkv8(const bf16s* __restrict__ xb, const bf16s* __restrict__ WqT,
               const bf16s* __restrict__ WkT, const bf16s* __restrict__ WvT,
               bf16s* __restrict__ qb, bf16s* __restrict__ kb,
               bf16s* __restrict__ vb) {
  const int bn = blockIdx.x, bm = blockIdx.y;
  const int im = bn >> 3, bnl = bn & 7;
  const bf16s* Bt = (im == 0) ? WqT : (im == 1 ? WkT : WvT);
  bf16s* out = (im == 0) ? qb : (im == 1 ? kb : vb);
  gemm8p_body<256, bf16s>(xb, Bt, out, bm, bnl, im < 2);
}

// output projection: grid (16, 16), BN=128 -> exactly 256 blocks
__global__ __launch_bounds__(512, 2)
void gemm_out8(const bf16s* __restrict__ ob, const bf16s* __restrict__ WoT,
               float* __restrict__ out) {
  gemm8p_body<128, float>(ob, WoT, out, blockIdx.y, blockIdx.x, 0);
}

// ============ chunked linear attention, 3-pass parallel decomposition =======
// Pass 1: per (b,h,c): M_c[f][e] = sum_i v_i[f] * k_i[e] * exp(tot-cum_i)
__global__ __launch_bounds__(256)
void chunk_state(const bf16s* __restrict__ k, const bf16s* __restrict__ v,
                 const float* __restrict__ ldp, bf16s* __restrict__ Mbuf,
                 float* __restrict__ totb) {
  const int c = blockIdx.x, bh = blockIdx.y;
  const int b = bh >> 4, h = bh & 15;
  const int t = threadIdx.x;
  const int w = t >> 6, l = t & 63;
  const int lr = l & 15, lk = l >> 4;

  __shared__ bf16s Kt[64 * 128];
  __shared__ bf16s Vn[64 * 128];
  __shared__ bf16s KdT[128 * 64];
  __shared__ bf16s VtT[128 * 64];
  __shared__ float cumS[64];
  char* cKt = (char*)Kt; char* cVn = (char*)Vn;
  char* cKdT = (char*)KdT; char* cVtT = (char*)VtT;

  const size_t grow0 = (size_t)b * NSEQ_ + c * 64;
#pragma unroll
  for (int j = 0; j < 4; ++j) {
    const int lrow = w * 16 + j * 4 + (l >> 4);
    const int ck = (l & 15) ^ (lrow & 7);
    const size_t goff = (grow0 + lrow) * D_ + h * E_ + ck * 8;
    const int lbase = (w * 16 + j * 4) * 128;
    gload_lds16(&k[goff], &Kt[lbase]);
    gload_lds16(&v[goff], &Vn[lbase]);
  }
  if (w == 0) {
    float val = ldp[(grow0 + l) * H_ + h];
#pragma unroll
    for (int off = 1; off < 64; off <<= 1) {
      float pv = __shfl_up(val, off);
      if (l >= off) val += pv;
    }
    cumS[l] = val;
  }
  __syncthreads();
  const float tot = cumS[63];
  if (t == 0) totb[bh * NCH_ + c] = tot;

  // transposes: VtT[f][i]=v_i[f], KdT[e][i]=k_i[e]*exp(tot-cum_i)
#pragma unroll
  for (int it = 0; it < 4; ++it) {
    const int task = t + it * 256;
    const int i = task >> 4, cx = task & 15;
    const int sb = i * 256 + ((cx * 16) ^ ((i & 7) << 4));
    bf16x8 vv = *(const bf16x8*)(cVn + sb);
    bf16x8 kk8 = *(const bf16x8*)(cKt + sb);
    const float sE = __expf(tot - cumS[i]);
#pragma unroll
    for (int jj = 0; jj < 8; ++jj) {
      const int e = cx * 8 + jj;
      const int db = e * 128 + ((i * 2) ^ ((e & 7) << 4));
      *(bf16s*)(cVtT + db) = vv[jj];
      *(bf16s*)(cKdT + db) = f2b(b2f(kk8[jj]) * sE);
    }
  }
  __syncthreads();

  const int wm = w >> 1, wn = w & 1;
  f32x4 acc[4][4] = {};
#pragma unroll
  for (int kk2 = 0; kk2 < 2; ++kk2) {
    const int cb = (kk2 * 32 + lk * 8) * 2;
    bf16x8 af[4], bfr[4];
#pragma unroll
    for (int tm = 0; tm < 4; ++tm) {
      const int fr = wm * 64 + tm * 16 + lr;
      af[tm] = *(const bf16x8*)(cVtT + fr * 128 + (cb ^ ((fr & 7) << 4)));
    }
#pragma unroll
    for (int tn = 0; tn < 4; ++tn) {
      const int er = wn * 64 + tn * 16 + lr;
      bfr[tn] = *(const bf16x8*)(cKdT + er * 128 + (cb ^ ((er & 7) << 4)));
    }
#pragma unroll
    for (int tm = 0; tm < 4; ++tm)
#pragma unroll
      for (int tn = 0; tn < 4; ++tn)
        acc[tm][tn] = __builtin_amdgcn_mfma_f32_16x16x32_bf16(
            af[tm], bfr[tn], acc[tm][tn], 0, 0, 0);
  }
  const size_t mb = (size_t)(bh * NCH_ + c) * 128 * 128;
#pragma unroll
  for (int tm = 0; tm < 4; ++tm) {
#pragma unroll
    for (int tn = 0; tn < 4; ++tn) {
#pragma unroll
      for (int r = 0; r < 4; ++r) {
        const int f = wm * 64 + tm * 16 + lk * 4 + r;
        const int e = wn * 64 + tn * 16 + lr;
        Mbuf[mb + f * 128 + e] = f2b(acc[tm][tn][r]);
      }
    }
  }
}

// Pass 2: prefix scan over chunks: S_{c+1} = exp(tot_c)*S_c + M_c.
// Writes S_c (state BEFORE chunk c), layout [bh][c][f][e] bf16.
__global__ __launch_bounds__(256)
void state_scan(const bf16s* __restrict__ Mbuf, const float* __restrict__ totb,
                bf16s* __restrict__ Sbuf) {
  const int sl = blockIdx.x;   // f-slice 0..7
  const int bh = blockIdx.y;   // 0..31
  const int t = threadIdx.x;
  const int fr = sl * 16 + (t >> 4);
  const int e0 = (t & 15) * 8;
  const size_t base = ((size_t)(bh * NCH_) * 128 + fr) * 128 + e0;
  const size_t cstride = 128 * 128;
  float acc[8] = {};
  bf16x8 m = *(const bf16x8*)&Mbuf[base];
  for (int c = 0; c < NCH_; ++c) {
    bf16x8 sv;
#pragma unroll
    for (int j = 0; j < 8; ++j) sv[j] = f2b(acc[j]);
    *(bf16x8*)&Sbuf[base + (size_t)c * cstride] = sv;
    bf16x8 mn = m;
    if (c + 1 < NCH_) mn = *(const bf16x8*)&Mbuf[base + (size_t)(c + 1) * cstride];
    const float dt = __expf(totb[bh * NCH_ + c]);
#pragma unroll
    for (int j = 0; j < 8; ++j) acc[j] = acc[j] * dt + b2f(m[j]);
    m = mn;
  }
}

// Pass 3: per (b,h,c): o = intra(q,k,v,decay) + exp(cum_i) * q @ S_c
__global__ __launch_bounds__(256)
void attn_out(const bf16s* __restrict__ q, const bf16s* __restrict__ k,
              const bf16s* __restrict__ v, const float* __restrict__ ldp,
              const bf16s* __restrict__ Sbuf, bf16s* __restrict__ o) {
  const int c = blockIdx.x, bh = blockIdx.y;
  const int b = bh >> 4, h = bh & 15;
  const int t = threadIdx.x;
  const int w = t >> 6, l = t & 63;
  const int lr = l & 15, lk = l >> 4;

  __shared__ bf16s Qt[64 * 128];
  __shared__ bf16s Kt[64 * 128];
  __shared__ bf16s Vn[64 * 128];
  __shared__ bf16s VtT[128 * 64];
  __shared__ bf16s St[128 * 128];  // S^T[f][e], swizzled
  __shared__ bf16s Pm[64 * 64];
  __shared__ float cumS[64];
  char* cQt = (char*)Qt; char* cKt = (char*)Kt; char* cVn = (char*)Vn;
  char* cVtT = (char*)VtT; char* cSt = (char*)St; char* cPm = (char*)Pm;

  const size_t grow0 = (size_t)b * NSEQ_ + c * 64;
  const size_t sbase = (size_t)(bh * NCH_ + c) * 128 * 128;
#pragma unroll
  for (int j = 0; j < 4; ++j) {
    const int lrow = w * 16 + j * 4 + (l >> 4);
    const int ck = (l & 15) ^ (lrow & 7);
    const size_t goff = (grow0 + lrow) * D_ + h * E_ + ck * 8;
    const int lbase = (w * 16 + j * 4) * 128;
    gload_lds16(&q[goff], &Qt[lbase]);
    gload_lds16(&k[goff], &Kt[lbase]);
    gload_lds16(&v[goff], &Vn[lbase]);
  }
#pragma unroll
  for (int j = 0; j < 8; ++j) {
    const int lrow = w * 32 + j * 4 + (l >> 4);
    const int ck = (l & 15) ^ (lrow & 7);
    gload_lds16(&Sbuf[sbase + (size_t)lrow * 128 + ck * 8],
                &St[(w * 32 + j * 4) * 128]);
  }
  if (w == 0) {
    float val = ldp[(grow0 + l) * H_ + h];
#pragma unroll
    for (int off = 1; off < 64; off <<= 1) {
      float pv = __shfl_up(val, off);
      if (l >= off) val += pv;
    }
    cumS[l] = val;
  }
  __syncthreads();

  // VtT[f][i] = v_i[f]
#pragma unroll
  for (int it = 0; it < 4; ++it) {
    const int task = t + it * 256;
    const int i = task >> 4, cx = task & 15;
    const int sb = i * 256 + ((cx * 16) ^ ((i & 7) << 4));
    bf16x8 vv = *(const bf16x8*)(cVn + sb);
#pragma unroll
    for (int jj = 0; jj < 8; ++jj) {
      const int e = cx * 8 + jj;
      const int db = e * 128 + ((i * 2) ^ ((e & 7) << 4));
      *(bf16s*)(cVtT + db) = vv[jj];
    }
  }

  f32x4 accs[4] = {};
  f32x4 acco[8] = {};
#pragma unroll
  for (int kk = 0; kk < 4; ++kk) {
    const int cb = (kk * 32 + lk * 8) * 2;
    const int ar = w * 16 + lr;
    bf16x8 aq = *(const bf16x8*)(cQt + ar * 256 + (cb ^ ((ar & 7) << 4)));
#pragma unroll
    for (int tn = 0; tn < 4; ++tn) {
      const int br = tn * 16 + lr;
      bf16x8 bk = *(const bf16x8*)(cKt + br * 256 + (cb ^ ((br & 7) << 4)));
      accs[tn] = __builtin_amdgcn_mfma_f32_16x16x32_bf16(aq, bk, accs[tn], 0, 0, 0);
    }
#pragma unroll
    for (int tf = 0; tf < 8; ++tf) {
      const int sr = tf * 16 + lr;
      bf16x8 bs = *(const bf16x8*)(cSt + sr * 256 + (cb ^ ((sr & 7) << 4)));
      acco[tf] = __builtin_amdgcn_mfma_f32_16x16x32_bf16(aq, bs, acco[tf], 0, 0, 0);
    }
  }
#pragma unroll
  for (int r = 0; r < 4; ++r) {
    const float gI = __expf(cumS[w * 16 + lk * 4 + r]);
#pragma unroll
    for (int tf = 0; tf < 8; ++tf) acco[tf][r] *= gI;
  }
#pragma unroll
  for (int tn = 0; tn < 4; ++tn) {
    const int j = tn * 16 + lr;
    const float cj = cumS[j];
#pragma unroll
    for (int r = 0; r < 4; ++r) {
      const int i = w * 16 + lk * 4 + r;
      const float sv = (j <= i) ? accs[tn][r] * __expf(cumS[i] - cj) : 0.f;
      *(bf16s*)(cPm + i * 128 + ((j * 2) ^ ((i & 7) << 4))) = f2b(sv);
    }
  }
  __syncthreads();

#pragma unroll
  for (int kk2 = 0; kk2 < 2; ++kk2) {
    const int cb = (kk2 * 32 + lk * 8) * 2;
    const int pr = w * 16 + lr;
    bf16x8 ap = *(const bf16x8*)(cPm + pr * 128 + (cb ^ ((pr & 7) << 4)));
#pragma unroll
    for (int tf = 0; tf < 8; ++tf) {
      const int fr = tf * 16 + lr;
      bf16x8 bv = *(const bf16x8*)(cVtT + fr * 128 + (cb ^ ((fr & 7) << 4)));
      acco[tf] = __builtin_amdgcn_mfma_f32_16x16x32_bf16(ap, bv, acco[tf], 0, 0, 0);
    }
  }
#pragma unroll
  for (int tf = 0; tf < 8; ++tf) {
#pragma unroll
    for (int r = 0; r < 4; ++r) {
      const int i = w * 16 + lk * 4 + r;
      o[(grow0 + i) * D_ + h * E_ + tf * 16 + lr] = f2b(acco[tf][r]);
    }
  }
}

// ---------------- in-place RMS norm over D ----------------
__global__ __launch_bounds__(256)
void rmsnorm(bf16s* __restrict__ o, const float* __restrict__ nw) {
  const int tok = blockIdx.x;
  const int t = threadIdx.x;
  bf16s* row = o + (size_t)tok * D_;
  bf16x8 vv = *(bf16x8*)&row[t * 8];
  float f[8];
  float s = 0.f;
#pragma unroll
  for (int j = 0; j < 8; ++j) { f[j] = b2f(vv[j]); s += f[j] * f[j]; }
#pragma unroll
  for (int off2 = 32; off2 > 0; off2 >>= 1) s += __shfl_down(s, off2);
  __shared__ float wsum[4];
  if ((t & 63) == 0) wsum[t >> 6] = s;
  __syncthreads();
  const float scale =
      rsqrtf((wsum[0] + wsum[1] + wsum[2] + wsum[3]) * (1.f / D_) + 1e-6f);
  bf16x8 ov;
#pragma unroll
  for (int j = 0; j < 8; ++j) ov[j] = f2b(f[j] * scale * nw[t * 8 + j]);
  *(bf16x8*)&row[t * 8] = ov;
}

extern "C" void kernel_launch(void* const* d_in, const int* in_sizes, int n_in,
                              void* d_out, int out_size, void* d_ws,
                              size_t ws_size, hipStream_t stream) {
  (void)in_sizes; (void)n_in; (void)out_size;
  const float* x  = (const float*)d_in[0];
  const float* Wq = (const float*)d_in[1];
  const float* Wk = (const float*)d_in[2];
  const float* Wv = (const float*)d_in[3];
  const float* Wf = (const float*)d_in[4];
  const float* Wo = (const float*)d_in[5];
  const float* nw = (const float*)d_in[6];
  float* out = (float*)d_out;

  char* ws = (char*)d_ws;
  const size_t MB = 1024 * 1024;
  // Region A (0..40MB): xb + WqT/WkT/WvT early; Sbuf + totb after gemm_qkv8.
  bf16s* xb   = (bf16s*)(ws + 0);
  bf16s* WqT  = (bf16s*)(ws + 16 * MB);
  bf16s* WkT  = (bf16s*)(ws + 24 * MB);
  bf16s* WvT  = (bf16s*)(ws + 32 * MB);
  bf16s* Sbuf = (bf16s*)(ws + 0);        // alias: live after gemm_qkv8
  float* totb = (float*)(ws + 32 * MB);  // alias: live after gemm_qkv8
  bf16s* WoT  = (bf16s*)(ws + 40 * MB);
  bf16s* qb   = (bf16s*)(ws + 48 * MB);
  bf16s* kb   = (bf16s*)(ws + 64 * MB);
  bf16s* vb   = (bf16s*)(ws + 80 * MB);
  bf16s* ob   = (bf16s*)(ws + 96 * MB);
  bf16s* Mbuf = (bf16s*)(ws + 112 * MB);
  float* ldb  = (float*)(ws + 144 * MB);
  if (145 * MB > ws_size) return;  // workspace too small -> clean fail

  cvt_bf16<<<NTOK_ * D_ / 8 / 256, 256, 0, stream>>>(x, xb);
  transpose_w<<<dim3(32, 32, 4), 256, 0, stream>>>(Wq, Wk, Wv, Wo, WqT, WkT,
                                                   WvT, WoT);
  ld_gemm<<<NTOK_ / 16, 256, 0, stream>>>(x, Wf, ldb);
  gemm_qkv8<<<dim3(24, 16), 512, 0, stream>>>(xb, WqT, WkT, WvT, qb, kb, vb);
  chunk_state<<<dim3(NCH_, NB_ * H_), 256, 0, stream>>>(kb, vb, ldb, Mbuf, totb);
  state_scan<<<dim3(8, NB_ * H_), 256, 0, stream>>>(Mbuf, totb, Sbuf);
  attn_out<<<dim3(NCH_, NB_ * H_), 256, 0, stream>>>(qb, kb, vb, ldb, Sbuf, ob);
  rmsnorm<<<NTOK_, 256, 0, stream>>>(ob, nw);
  gemm_out8<<<dim3(16, 16), 512, 0, stream>>>(ob, WoT, out);
}